// Round 6
// baseline (389.908 us; speedup 1.0000x reference)
//
#include <hip/hip_runtime.h>
#include <stdint.h>

#define B_DIM 4096
#define IN_SZ 1024
#define HID   2048
#define D_DIM 3072   // K = IN_SZ + HID
#define BM 256       // batch rows per block
#define BN 64        // h-columns per block (x4 gates = 256 logical cols)
#define BK 64        // K-step (bf16 elems)
#define NT (D_DIM / BK)   // 48

typedef float  f32x4  __attribute__((ext_vector_type(4)));
typedef short  short8 __attribute__((ext_vector_type(8)));

__device__ __forceinline__ unsigned short f2bf(float f) {
    union { float f; unsigned u; } v; v.f = f;
    unsigned u = v.u + 0x7fffu + ((v.u >> 16) & 1u);   // RNE
    return (unsigned short)(u >> 16);
}

__device__ __forceinline__ void async_load16(const void* g, void* l) {
    __builtin_amdgcn_global_load_lds(
        (const __attribute__((address_space(1))) unsigned int*)g,
        (__attribute__((address_space(3))) unsigned int*)l,
        16, 0, 0);
}

__device__ __forceinline__ float sigm(float x) {
    return 1.0f / (1.0f + __expf(-x));
}
__device__ __forceinline__ float tanh_f(float x) {
    return 1.0f - 2.0f / (__expf(2.0f * x) + 1.0f);
}

// ---- prepass ----
// A: concat(x,h) -> bf16 [B][D] (linear).
// W: fragment-record order. 16-B record index wi = (((c*NT+kt)*4+wn)*8 + j*2+s)*64 + l:
//    element e of record = W_gate[j][ c*64 + wn*16 + (l&15) ][ kt*64 + s*32 + (l>>4)*8 + e ]
//    -> a wave's B-fragment load is one contiguous 1-KB read.
__global__ __launch_bounds__(256)
void convert_all(const float* __restrict__ x, const float* __restrict__ h,
                 const float* __restrict__ W0, const float* __restrict__ W1,
                 const float* __restrict__ W2, const float* __restrict__ W3,
                 unsigned short* __restrict__ Abf, unsigned short* __restrict__ Wbf) {
    const int NA = B_DIM * D_DIM / 8;        // 1,572,864
    const int NW = 4 * HID * D_DIM / 8;      // 3,145,728
    int idx = blockIdx.x * blockDim.x + threadIdx.x;
    const float* src;
    unsigned short* dst;
    if (idx < NA) {
        const int C8 = D_DIM / 8;            // 384
        int b = idx / C8, c8 = idx - b * C8;
        src = (c8 < IN_SZ / 8) ? x + (size_t)b * IN_SZ + c8 * 8
                               : h + (size_t)b * HID + (c8 - IN_SZ / 8) * 8;
        dst = Abf + (size_t)idx * 8;
    } else {
        int wi = idx - NA;
        if (wi >= NW) return;
        int l  = wi & 63;
        int q  = wi >> 6;                    // (((c*NT+kt)*4+wn)*8 + j*2+s)
        int s  = q & 1;
        int j  = (q >> 1) & 3;
        int wn = (q >> 3) & 3;
        int q3 = q >> 5;                     // c*NT + kt
        int kt = q3 % NT;
        int c  = q3 / NT;
        const float* W = (j == 0) ? W0 : (j == 1) ? W1 : (j == 2) ? W2 : W3;
        int hrow = c * 64 + wn * 16 + (l & 15);
        int k    = kt * 64 + s * 32 + (l >> 4) * 8;
        src = W + (size_t)hrow * D_DIM + k;
        dst = Wbf + (size_t)wi * 8;
    }
    float4 v0 = ((const float4*)src)[0];
    float4 v1 = ((const float4*)src)[1];
    short8 o;
    o[0] = (short)f2bf(v0.x); o[1] = (short)f2bf(v0.y);
    o[2] = (short)f2bf(v0.z); o[3] = (short)f2bf(v0.w);
    o[4] = (short)f2bf(v1.x); o[5] = (short)f2bf(v1.y);
    o[6] = (short)f2bf(v1.z); o[7] = (short)f2bf(v1.w);
    *(short8*)dst = o;
}

// ---------- MFMA cluster: 16 MFMAs = m-frags [IB..IB+4) x 4 n-frags, k-slice S
template <int IB, int S>
__device__ __forceinline__ void mfma16(f32x4 (&acc)[8][4], const short8 (&a)[4],
                                       const short8 (&b)[4][2]) {
#pragma unroll
    for (int i = 0; i < 4; ++i)
#pragma unroll
        for (int j = 0; j < 4; ++j)
            acc[IB + i][j] = __builtin_amdgcn_mfma_f32_16x16x32_bf16(
                a[i], b[j][S], acc[IB + i][j], 0, 0, 0);
}

// One K-tile = 4 phases. B lives in REGISTERS (loaded direct from the pre-
// transposed Wbf, double-buffered bc/bn, issued a full tile ahead). LDS holds
// only A (2 x 32 KB double buffer). A-frag batches read one phase ahead:
//   ph1: read F1+F2; issue Bn (8 x 1KB coalesced) + A-stage (4 gload_lds); MFMA1(F1,bc s0)
//   ph2: read F3; MFMA2(F2, bc s0)
//   ph3: read F4; MFMA3(F3, bc s1)
//   ph4: MFMA4(F4, bc s1); vmcnt(0) (loads have ~full tile of slack); barrier
// MODE: 1 = steady, 0 = last tile (no loads, no barrier).
template <int MODE>
__device__ __forceinline__ void tile_body(
    f32x4 (&acc)[8][4], const short8 (&bc)[4][2], short8 (&bn)[4][2],
    const char* cur, char* nxt,
    const unsigned short* pBn,   // next tile's B records (this wave/lane)
    const unsigned short* srcA0, // A stage source (this wave/lane), k=0
    int koff, int chunk, int aBase, int sw0, int sw1) {
    short8 f1[4], f2[4], f3[4], f4[4];

    // ================= phase 1: MFMA m0-3 x s0 =================
#pragma unroll
    for (int i = 0; i < 4; ++i)
        f1[i] = *(const short8*)(cur + aBase + i * 2048 + sw0);
#pragma unroll
    for (int i = 0; i < 4; ++i)
        f2[i] = *(const short8*)(cur + aBase + (4 + i) * 2048 + sw0);
    if (MODE) {
#pragma unroll
        for (int j = 0; j < 4; ++j) {
            bn[j][0] = *(const short8*)(pBn + (j * 2 + 0) * 512);
            bn[j][1] = *(const short8*)(pBn + (j * 2 + 1) * 512);
        }
#pragma unroll
        for (int i = 0; i < 4; ++i)
            async_load16(srcA0 + i * 8 * D_DIM + koff, nxt + chunk + i * 1024);
    }
    __builtin_amdgcn_sched_barrier(0);
    __builtin_amdgcn_s_setprio(1);
    mfma16<0, 0>(acc, f1, bc);
    __builtin_amdgcn_s_setprio(0);

    // ================= phase 2: MFMA m4-7 x s0 =================
#pragma unroll
    for (int i = 0; i < 4; ++i)
        f3[i] = *(const short8*)(cur + aBase + i * 2048 + sw1);
    __builtin_amdgcn_sched_barrier(0);
    __builtin_amdgcn_s_setprio(1);
    mfma16<4, 0>(acc, f2, bc);
    __builtin_amdgcn_s_setprio(0);

    // ================= phase 3: MFMA m0-3 x s1 =================
#pragma unroll
    for (int i = 0; i < 4; ++i)
        f4[i] = *(const short8*)(cur + aBase + (4 + i) * 2048 + sw1);
    __builtin_amdgcn_sched_barrier(0);
    __builtin_amdgcn_s_setprio(1);
    mfma16<0, 1>(acc, f3, bc);
    __builtin_amdgcn_s_setprio(0);

    // ================= phase 4: MFMA m4-7 x s1 =================
    __builtin_amdgcn_sched_barrier(0);
    __builtin_amdgcn_s_setprio(1);
    mfma16<4, 1>(acc, f4, bc);
    __builtin_amdgcn_s_setprio(0);
    if (MODE) {
        asm volatile("s_waitcnt vmcnt(0)" ::: "memory");   // B-next + A-stage landed
        __builtin_amdgcn_s_barrier();                      // single barrier per tile
        asm volatile("" ::: "memory");
    }
}

// ---- fused gate-GEMM + LSTM epilogue, 256x(64h x 4gates), BK=64, 8 waves ----
// col = h_hi*64 + gate*16 + h_lo -> all 4 gates of an (m,h) share a lane.
// LDS: A only, 2 x 32 KB, [row][64] bf16 (128-B rows) with slot^=row&7 XOR swizzle
// on BOTH the pre-swizzled staging source and the ds_read offset.
// XCD swizzle: blocks sharing the same h-panel (c) land on one XCD for B-L2 reuse.
__global__ __launch_bounds__(512, 2)
void lstm_gemm(const unsigned short* __restrict__ Abf,   // [B][D] bf16
               const unsigned short* __restrict__ Wbf,   // fragment-record order
               const float* __restrict__ b_i, const float* __restrict__ b_f,
               const float* __restrict__ b_c, const float* __restrict__ b_o,
               const float* __restrict__ c_prev,
               float* __restrict__ h_out, float* __restrict__ c_out) {
    extern __shared__ char sm[];   // 65536 B

    const int tid  = threadIdx.x;
    const int lane = tid & 63;
    const int wave = tid >> 6;          // 0..7
    const int wm   = wave >> 2;         // 0..1
    const int wn   = wave & 3;          // 0..3
    const int l16  = lane & 15;
    const int quad = lane >> 4;
    const int r7   = l16 & 7;

    // XCD-clustered role mapping: c = (hw&7) + 8*((hw>>3)&3)  (same c -> same hw&7)
    const int hwid = blockIdx.x;
    const int c    = (hwid & 7) + 8 * ((hwid >> 3) & 3);   // h-block 0..31
    const int bx   = hwid >> 5;                            // m-block 0..15
    const int m0 = bx * BM;
    const int h0 = c * BN;

    // A staging: instr (wave,i) covers rows (wave*4+i)*8..+8 (128 B each)
    const int g8 = lane >> 3;           // row within octet
    const int sl = (lane & 7) ^ g8;     // pre-swizzled source slot (involution)
    const unsigned short* srcA0 = Abf + (size_t)(m0 + wave * 32 + g8) * D_DIM + sl * 8;
    const int chunk = wave * 4096;      // per-wave stage region (+i*1024)

    // B records for this wave: base of (c, kt=0, wn), per-lane
    const unsigned short* pB = Wbf + ((size_t)(c * NT) * 4 + wn) * 4096 + lane * 8;

    // ds_read offsets: addr = row*128 + ((s*4+quad)^(row&7))*16, row&7 == l16&7
    const int aBase = (wm * 128 + l16) * 128;
    const int sw0 = ((0 * 4 + quad) ^ r7) * 16;
    const int sw1 = ((1 * 4 + quad) ^ r7) * 16;

    f32x4 acc[8][4] = {};
    short8 b0[4][2], b1[4][2];

    // ---- prologue: B tile0 -> b0 (regs), stage A tile0 -> buf0 ----
#pragma unroll
    for (int j = 0; j < 4; ++j) {
        b0[j][0] = *(const short8*)(pB + (j * 2 + 0) * 512);
        b0[j][1] = *(const short8*)(pB + (j * 2 + 1) * 512);
    }
#pragma unroll
    for (int i = 0; i < 4; ++i)
        async_load16(srcA0 + i * 8 * D_DIM, sm + chunk + i * 1024);
    asm volatile("s_waitcnt vmcnt(0)" ::: "memory");
    __builtin_amdgcn_s_barrier();
    asm volatile("" ::: "memory");
    pB += 16384;                        // advance to tile-1 records

    for (int kt = 0; kt < NT - 2; kt += 2) {
        const char* e = sm + (kt & 1) * 32768;          // even buffer
        char*       o = (char*)sm + ((kt + 1) & 1) * 32768;
        tile_body<1>(acc, b0, b1, e, o, pB, srcA0, (kt + 1) * BK,
                     chunk, aBase, sw0, sw1);
        pB += 16384;
        tile_body<1>(acc, b1, b0, o, (char*)e, pB, srcA0, (kt + 2) * BK,
                     chunk, aBase, sw0, sw1);
        pB += 16384;
    }
    {   // tile NT-2 (even -> buf0): steady (loads B/A for last tile)
        tile_body<1>(acc, b0, b1, sm, (char*)sm + 32768, pB, srcA0,
                     (NT - 1) * BK, chunk, aBase, sw0, sw1);
    }
    {   // tile NT-1 (odd -> buf1): last
        tile_body<0>(acc, b1, b0, sm + 32768, (char*)sm, pB, srcA0,
                     0, chunk, aBase, sw0, sw1);
    }

    // ---- epilogue: C layout col = lane&15, row = quad*4 + reg ----
    const int h = h0 + wn * 16 + l16;
    const float biv = b_i[h], bfv = b_f[h], bcv = b_c[h], bov = b_o[h];
    const int mb = m0 + wm * 128 + quad * 4;
#pragma unroll
    for (int i = 0; i < 8; ++i) {
#pragma unroll
        for (int r = 0; r < 4; ++r) {
            const int m = mb + i * 16 + r;
            const size_t off = (size_t)m * HID + h;
            const float gi = acc[i][0][r] + biv;
            const float gf = acc[i][1][r] + bfv;
            const float gc = acc[i][2][r] + bcv;
            const float go = acc[i][3][r] + bov;
            const float it = sigm(gi), ft = sigm(gf);
            const float gt = tanh_f(gc), ot = sigm(go);
            const float cc = ft * c_prev[off] + it * gt;
            h_out[off] = ot * tanh_f(cc);
            c_out[off] = cc;
        }
    }
}

extern "C" void kernel_launch(void* const* d_in, const int* in_sizes, int n_in,
                              void* d_out, int out_size, void* d_ws, size_t ws_size,
                              hipStream_t stream) {
    const float* x_t    = (const float*)d_in[0];
    const float* h_prev = (const float*)d_in[1];
    const float* c_prev = (const float*)d_in[2];
    const float* W_i = (const float*)d_in[3];
    const float* b_i = (const float*)d_in[4];
    const float* W_f = (const float*)d_in[5];
    const float* b_f = (const float*)d_in[6];
    const float* W_c = (const float*)d_in[7];
    const float* b_c = (const float*)d_in[8];
    const float* W_o = (const float*)d_in[9];
    const float* b_o = (const float*)d_in[10];
    float* out = (float*)d_out;

    unsigned short* Abf = (unsigned short*)d_ws;                       // 25,165,824 B
    unsigned short* Wbf = (unsigned short*)((char*)d_ws + (size_t)B_DIM * D_DIM * 2);
    // total ws use: 25.2 MB + 50.3 MB = 75,497,472 B (== ws budget)

    static bool s_attr = false;
    if (!s_attr) {
        (void)hipFuncSetAttribute((const void*)lstm_gemm,
                                  hipFuncAttributeMaxDynamicSharedMemorySize, 65536);
        s_attr = true;
    }

    {
        const int n = (B_DIM * D_DIM + 4 * HID * D_DIM) / 8;   // 4,718,592
        convert_all<<<n / 256, 256, 0, stream>>>(x_t, h_prev, W_i, W_f, W_c, W_o,
                                                 Abf, Wbf);
    }
    lstm_gemm<<<512, 512, 65536, stream>>>(Abf, Wbf, b_i, b_f, b_c, b_o, c_prev,
                                           out, out + (size_t)B_DIM * HID);
}